// Round 2
// baseline (38.525 us; speedup 1.0000x reference)
//
#include <hip/hip_runtime.h>

// One 64-lane wave per voxel. Lane p loads point p's full float4 (coalesced,
// 16B/lane); label = (int)w. Histogram via 7x ballot+popcount; class 0 forced
// to count 0 per reference; strict > gives first-max argmax semantics.
// Output buffer is int32 (int64 reference -> harness int32 readback path).
__global__ void voxel_majority_kernel(const float4* __restrict__ feats,
                                      int* __restrict__ out,
                                      const int* __restrict__ class_num_p,
                                      int n_voxels) {
    const int lane = threadIdx.x & 63;
    const int wave_in_block = threadIdx.x >> 6;
    const int waves_per_block = blockDim.x >> 6;
    const int v = blockIdx.x * waves_per_block + wave_in_block;
    if (v >= n_voxels) return;

    const int K = *class_num_p;  // broadcast scalar read (L2-cached)

    // Point layout: [N, 64, 4] f32 -> voxel v, point lane at float4 index v*64+lane
    float4 pt = feats[(size_t)v * 64 + lane];
    int label = (int)pt.w;

    int best_idx = 0;
    int best_cnt = 0;  // class 0 count forced to 0 by reference
    #pragma unroll 7
    for (int k = 1; k < K; ++k) {
        unsigned long long m = __ballot(label == k);
        int c = __popcll(m);
        if (c > best_cnt) { best_cnt = c; best_idx = k; }  // strict >: first max wins
    }

    if (lane == 0) out[v] = best_idx;
}

extern "C" void kernel_launch(void* const* d_in, const int* in_sizes, int n_in,
                              void* d_out, int out_size, void* d_ws, size_t ws_size,
                              hipStream_t stream) {
    const float4* feats = (const float4*)d_in[0];
    const int* class_num_p = (const int*)d_in[1];
    int* out = (int*)d_out;

    const int n_voxels = in_sizes[0] / (64 * 4);  // [N, P=64, C=4]

    const int block = 256;                   // 4 waves/block
    const int waves_per_block = block / 64;
    const int grid = (n_voxels + waves_per_block - 1) / waves_per_block;

    voxel_majority_kernel<<<grid, block, 0, stream>>>(feats, out, class_num_p, n_voxels);
}

// Round 3
// 34.226 us; speedup vs baseline: 1.1256x; 1.1256x over previous
//
#include <hip/hip_runtime.h>

// 4 voxels per 64-lane wave. Lane p loads ONLY the label float of point p for
// each of the 4 voxels (4B at stride 16B, 4 independent loads -> MLP=4, same
// cache-line footprint as float4 loads). Histogram via 7x ballot+popcount;
// class 0 forced to 0 per reference; strict > = first-max argmax. Packed int4
// store. Output buffer is int32 (int64 reference -> harness int32 readback).
__global__ void voxel_majority_kernel(const float* __restrict__ feats,
                                      int* __restrict__ out,
                                      const int* __restrict__ class_num_p,
                                      int n_voxels) {
    const int lane = threadIdx.x & 63;
    const int wave = (blockIdx.x * blockDim.x + threadIdx.x) >> 6;
    const int v0 = wave * 4;
    if (v0 >= n_voxels) return;

    const int K = *class_num_p;

    // label address for voxel v, point lane: ((v*64 + lane)*4 + 3) floats
    const float* base = feats + ((size_t)v0 * 64 + lane) * 4 + 3;

    if (v0 + 3 < n_voxels) {
        // Issue all 4 streaming loads back-to-back (independent -> MLP=4).
        float w0 = __builtin_nontemporal_load(base + 0 * 256);
        float w1 = __builtin_nontemporal_load(base + 1 * 256);
        float w2 = __builtin_nontemporal_load(base + 2 * 256);
        float w3 = __builtin_nontemporal_load(base + 3 * 256);
        int l0 = (int)w0, l1 = (int)w1, l2 = (int)w2, l3 = (int)w3;

        int bi0 = 0, bc0 = 0, bi1 = 0, bc1 = 0;
        int bi2 = 0, bc2 = 0, bi3 = 0, bc3 = 0;
        #pragma unroll 7
        for (int k = 1; k < K; ++k) {
            int c0 = __popcll(__ballot(l0 == k));
            int c1 = __popcll(__ballot(l1 == k));
            int c2 = __popcll(__ballot(l2 == k));
            int c3 = __popcll(__ballot(l3 == k));
            if (c0 > bc0) { bc0 = c0; bi0 = k; }
            if (c1 > bc1) { bc1 = c1; bi1 = k; }
            if (c2 > bc2) { bc2 = c2; bi2 = k; }
            if (c3 > bc3) { bc3 = c3; bi3 = k; }
        }

        if (lane == 0) {
            int4 r = make_int4(bi0, bi1, bi2, bi3);
            *reinterpret_cast<int4*>(out + v0) = r;  // v0 % 4 == 0 -> 16B aligned
        }
    } else {
        // Tail: per-voxel guarded path.
        for (int j = 0; j < 4; ++j) {
            int v = v0 + j;
            if (v >= n_voxels) break;
            float w = __builtin_nontemporal_load(base + j * 256);
            int l = (int)w;
            int bi = 0, bc = 0;
            for (int k = 1; k < K; ++k) {
                int c = __popcll(__ballot(l == k));
                if (c > bc) { bc = c; bi = k; }
            }
            if (lane == 0) out[v] = bi;
        }
    }
}

extern "C" void kernel_launch(void* const* d_in, const int* in_sizes, int n_in,
                              void* d_out, int out_size, void* d_ws, size_t ws_size,
                              hipStream_t stream) {
    const float* feats = (const float*)d_in[0];
    const int* class_num_p = (const int*)d_in[1];
    int* out = (int*)d_out;

    const int n_voxels = in_sizes[0] / (64 * 4);  // [N, P=64, C=4]

    const int block = 256;  // 4 waves/block
    const int voxels_per_wave = 4;
    const int waves = (n_voxels + voxels_per_wave - 1) / voxels_per_wave;
    const int waves_per_block = block / 64;
    const int grid = (waves + waves_per_block - 1) / waves_per_block;

    voxel_majority_kernel<<<grid, block, 0, stream>>>(feats, out, class_num_p, n_voxels);
}